// Round 8
// baseline (169.721 us; speedup 1.0000x reference)
//
#include <hip/hip_runtime.h>
#include <math.h>

#define BB 4
#define CC 256
#define HWN 4096
#define NTOK 16384                 // BB*HWN
#define SCQ 0.09016844136f         // (1/sqrt(256)) * log2(e)

typedef __attribute__((ext_vector_type(8))) short short8;
typedef __attribute__((ext_vector_type(4))) float f32x4;
typedef unsigned short ushort_t;

__device__ __forceinline__ ushort_t f2bf(float f) {
    unsigned int u = __float_as_uint(f);
    unsigned int r = (u + 0x7FFFu + ((u >> 16) & 1u)) >> 16;   // RNE
    return (ushort_t)r;
}
__device__ __forceinline__ unsigned int pack2(float a, float b) {
    return (unsigned int)f2bf(a) | ((unsigned int)f2bf(b) << 16);
}
__device__ __forceinline__ float fexp2(float x) {
#if __has_builtin(__builtin_amdgcn_exp2f)
    return __builtin_amdgcn_exp2f(x);     // single v_exp_f32
#else
    return exp2f(x);
#endif
}

// ---------------------------------------------------------------------------
// Kernel 0: prep. Blocks 0..1023: transpose feature [C][HW] fp32 -> fbuf
// [HW][C] bf16 (64x64 tiles via LDS). Blocks 1024..1087: convert q_w
// (pre-scaled by SCQ) and k_w to bf16; zero den/nx/ny.
// ---------------------------------------------------------------------------
__global__ __launch_bounds__(256) void prep_kernel(
    const float* __restrict__ feature,
    const float* __restrict__ q_w, const float* __restrict__ k_w,
    ushort_t* __restrict__ fbuf,
    ushort_t* __restrict__ qwb, ushort_t* __restrict__ kwb,
    float* __restrict__ zbuf)
{
    int bid = blockIdx.x;
    int tid = threadIdx.x;

    if (bid >= 1024) {                       // weight convert + zero
        int t = (bid - 1024) * 256 + tid;    // 0..16383
        float4 q4 = *(const float4*)&q_w[(size_t)t * 4];
        float4 k4 = *(const float4*)&k_w[(size_t)t * 4];
        unsigned long long qo = (unsigned long long)pack2(q4.x * SCQ, q4.y * SCQ)
                              | ((unsigned long long)pack2(q4.z * SCQ, q4.w * SCQ) << 32);
        unsigned long long ko = (unsigned long long)pack2(k4.x, k4.y)
                              | ((unsigned long long)pack2(k4.z, k4.w) << 32);
        *(unsigned long long*)&qwb[(size_t)t * 4] = qo;
        *(unsigned long long*)&kwb[(size_t)t * 4] = ko;
        zbuf[t] = 0.f; zbuf[t + NTOK] = 0.f; zbuf[t + 2 * NTOK] = 0.f;
        return;
    }

    // transpose tile: b (0..3), cch (0..3), nch (0..63)
    int b   = bid >> 8;
    int rem = bid & 255;
    int cch = rem >> 6;
    int nch = rem & 63;

    __shared__ float lsA[64][69];            // [c][n] fp32, stride 69

    int cl = tid >> 2, tg = (tid & 3) * 16;
    const float* src = feature + (size_t)(b * CC + cch * 64 + cl) * HWN + nch * 64 + tg;
    *(float4*)&lsA[cl][tg]      = *(const float4*)(src);
    *(float4*)&lsA[cl][tg + 4]  = *(const float4*)(src + 4);
    *(float4*)&lsA[cl][tg + 8]  = *(const float4*)(src + 8);
    *(float4*)&lsA[cl][tg + 12] = *(const float4*)(src + 12);
    __syncthreads();

    int tokw = tid >> 2, c16 = (tid & 3) * 16;
    unsigned int u[8];
    #pragma unroll
    for (int j = 0; j < 8; j++)
        u[j] = pack2(lsA[c16 + 2 * j][tokw], lsA[c16 + 2 * j + 1][tokw]);
    size_t orow = (size_t)(b * HWN + nch * 64 + tokw) * CC + cch * 64 + c16;
    *(uint4*)&fbuf[orow]     = *(uint4*)&u[0];
    *(uint4*)&fbuf[orow + 8] = *(uint4*)&u[4];
}

// ---------------------------------------------------------------------------
// Projection: register GEMM, no LDS/barriers. Block = 64 tokens x 64-d
// quarter. OUTPUT IS FRAGMENT-GRANULE MAJOR: granule g(b,tile16,kc,quad,n16)
// = X[tile*16+n16][kc*32+quad*8 .. +8] stored at byte ((b*256+tile)*512 +
// kc*64 + quad*16 + n16)*16.
// ---------------------------------------------------------------------------
__global__ __launch_bounds__(256, 2) void proj_kernel(
    const ushort_t* __restrict__ fbuf,
    const ushort_t* __restrict__ qwb, const ushort_t* __restrict__ kwb,
    const float* __restrict__ q_bias, const float* __restrict__ k_bias,
    ushort_t* __restrict__ qb, ushort_t* __restrict__ kb)
{
    int id = blockIdx.x;
    int dh = id >> 8;                 // 0..3 d-quarter
    int inner = id & 255;
    int b   = inner & 3;
    int tch = inner >> 2;             // 0..63
    int tok0 = tch * 64;

    int t = threadIdx.x, w = t >> 6, lane = t & 63;
    int n16 = lane & 15, quad = lane >> 4;

    int d0 = dh * 64 + w * 16;

    short8 aq[8], ak[8];
    #pragma unroll
    for (int kc = 0; kc < 8; kc++) {
        size_t off = (size_t)(d0 + n16) * CC + kc * 32 + quad * 8;
        aq[kc] = *(const short8*)&qwb[off];
        ak[kc] = *(const short8*)&kwb[off];
    }
    float bqv[4], bkv[4];
    #pragma unroll
    for (int r = 0; r < 4; r++) {
        bqv[r] = q_bias[d0 + quad * 4 + r] * SCQ;
        bkv[r] = k_bias[d0 + quad * 4 + r];
    }

    // fragment-granule store indices (loop-invariant parts)
    int kcq   = d0 >> 5;                          // kc of the granule
    int quadA = ((d0 >> 4) & 1) * 2 + (quad >> 1);// quad of the granule
    int halfo = quad & 1;                         // which 8B half

    #pragma unroll
    for (int tokt = 0; tokt < 4; tokt++) {
        size_t trow = (size_t)(b * HWN + tok0 + tokt * 16 + n16) * CC;
        short8 bf[8];
        #pragma unroll
        for (int kc = 0; kc < 8; kc++)
            bf[kc] = *(const short8*)&fbuf[trow + kc * 32 + quad * 8];
        f32x4 accq = (f32x4){0.f, 0.f, 0.f, 0.f};
        f32x4 acck = (f32x4){0.f, 0.f, 0.f, 0.f};
        #pragma unroll
        for (int kc = 0; kc < 8; kc++) {
            accq = __builtin_amdgcn_mfma_f32_16x16x32_bf16(aq[kc], bf[kc], accq, 0, 0, 0);
            acck = __builtin_amdgcn_mfma_f32_16x16x32_bf16(ak[kc], bf[kc], acck, 0, 0, 0);
        }
        ushort4 oq, ok;
        oq.x = f2bf(accq[0] + bqv[0]); oq.y = f2bf(accq[1] + bqv[1]);
        oq.z = f2bf(accq[2] + bqv[2]); oq.w = f2bf(accq[3] + bqv[3]);
        ok.x = f2bf(acck[0] + bkv[0]); ok.y = f2bf(acck[1] + bkv[1]);
        ok.z = f2bf(acck[2] + bkv[2]); ok.w = f2bf(acck[3] + bkv[3]);
        int tt_tile = tch * 4 + tokt;
        size_t gbyte = (((size_t)(b * 256 + tt_tile) * 512) + kcq * 64 + quadA * 16 + n16) * 16
                       + halfo * 8;
        *(ushort4*)((char*)qb + gbyte) = oq;
        *(ushort4*)((char*)kb + gbyte) = ok;
    }
}

// ---------------------------------------------------------------------------
// Attention v7 = verified round-6 kernel with ONE delta: after the staged
// Q + barrier (unchanged, verified path), Q fragments are hoisted LDS ->
// registers ONCE (qf[4][8] = 128 VGPR; same addresses the round-6 inner loop
// read 512x/wave). K round loop, flow LDS, swizzle, reduction all verbatim.
// launch_bounds(256,1) for the ~230 VGPR budget (2 blocks/CU).
// ---------------------------------------------------------------------------
__global__ __launch_bounds__(256, 1) void attn_kernel(
    const ushort_t* __restrict__ qb, const ushort_t* __restrict__ kb,
    const float* __restrict__ flow,
    float* __restrict__ den_g, float* __restrict__ nx_g, float* __restrict__ ny_g)
{
    int id = (blockIdx.x & 7) * 128 + (blockIdx.x >> 3);   // bijective XCD swizzle
    int qt = id & 63; id >>= 6;       // 64 q-tiles of 64 rows
    int sr = id & 3;  id >>= 2;       // 4 key ranges of 1024
    int b = id;

    int t = threadIdx.x;
    int w = t >> 6, lane = t & 63;
    int n16 = lane & 15, quad = lane >> 4;

    int q0 = qt * 64;
    int s_beg = sr * 1024;

    __shared__ __align__(16) ushort_t qlds[16384];   // 32 KB: 4 q-tiles, frag-major
    __shared__ float lflow[2048];                    // 1024 vx + 1024 vy

    const float* fx = flow + (size_t)b * 2 * HWN;
    const float* fy = fx + HWN;
    #pragma unroll
    for (int i = 0; i < 4; i++) {
        lflow[t + i * 256]        = fx[s_beg + t + i * 256];
        lflow[1024 + t + i * 256] = fy[s_beg + t + i * 256];
    }

    // stage Q block (4 tiles x 512 granules x 16B = 32KB), linear copy
    {
        const char* qsrc = (const char*)qb + ((size_t)(b * 256 + (q0 >> 4)) * 512) * 16;
        char* qdst = (char*)qlds;
        #pragma unroll
        for (int i = 0; i < 8; i++)
            __builtin_amdgcn_global_load_lds(
                (const __attribute__((address_space(1))) unsigned int*)(qsrc + (i * 256 + t) * 16),
                (__attribute__((address_space(3))) unsigned int*)(qdst + (i * 256 + t) * 16),
                16, 0, 0);
    }
    __syncthreads();   // only barrier: Q + flow staged

    // hoist Q LDS -> registers once (same addresses round-6 read in-loop)
    const char* qldsb = (const char*)qlds + (size_t)lane * 16;
    short8 qf[4][8];
    #pragma unroll
    for (int qtl = 0; qtl < 4; qtl++)
        #pragma unroll
        for (int kc = 0; kc < 8; kc++)
            qf[qtl][kc] = *(const short8*)(qldsb + qtl * 8192 + kc * 1024);

    // K granule base for this wave's 256-key quarter
    const char* kbase = (const char*)kb
        + ((size_t)(b * 256 + (s_beg >> 4) + w * 16) * 512 + lane) * 16;

    float den[4], nxa[4], nya[4];
    #pragma unroll
    for (int i = 0; i < 4; i++) { den[i] = 0.f; nxa[i] = 0.f; nya[i] = 0.f; }

    for (int round = 0; round < 8; round++) {
        short8 kf0[8], kf1[8];
        #pragma unroll
        for (int kc = 0; kc < 8; kc++) {
            kf0[kc] = *(const short8*)(kbase + (round * 2 + 0) * 8192 + kc * 1024);
            kf1[kc] = *(const short8*)(kbase + (round * 2 + 1) * 8192 + kc * 1024);
        }
        int klbase = w * 256 + round * 32 + quad * 4;
        f32x4 vx0 = *(const f32x4*)&lflow[klbase];
        f32x4 vx1 = *(const f32x4*)&lflow[klbase + 16];
        f32x4 vy0 = *(const f32x4*)&lflow[1024 + klbase];
        f32x4 vy1 = *(const f32x4*)&lflow[1024 + klbase + 16];

        #pragma unroll
        for (int qtl = 0; qtl < 4; qtl++) {
            f32x4 a0 = (f32x4){0.f, 0.f, 0.f, 0.f};
            f32x4 a1 = (f32x4){0.f, 0.f, 0.f, 0.f};
            #pragma unroll
            for (int kc = 0; kc < 8; kc++) {
                a0 = __builtin_amdgcn_mfma_f32_16x16x32_bf16(kf0[kc], qf[qtl][kc], a0, 0, 0, 0);
                a1 = __builtin_amdgcn_mfma_f32_16x16x32_bf16(kf1[kc], qf[qtl][kc], a1, 0, 0, 0);
            }
            float d_ = 0.f, x_ = 0.f, y_ = 0.f;
            #pragma unroll
            for (int r = 0; r < 4; r++) {
                float p0 = fexp2(a0[r]);
                float p1 = fexp2(a1[r]);
                d_ += p0 + p1;
                x_ = fmaf(p0, vx0[r], x_); x_ = fmaf(p1, vx1[r], x_);
                y_ = fmaf(p0, vy0[r], y_); y_ = fmaf(p1, vy1[r], y_);
            }
            den[qtl] += d_; nxa[qtl] += x_; nya[qtl] += y_;
        }
    }

    #pragma unroll
    for (int qtl = 0; qtl < 4; qtl++) {
        float dv = den[qtl], xv = nxa[qtl], yv = nya[qtl];
        dv += __shfl_down(dv, 32); dv += __shfl_down(dv, 16);
        xv += __shfl_down(xv, 32); xv += __shfl_down(xv, 16);
        yv += __shfl_down(yv, 32); yv += __shfl_down(yv, 16);
        if (lane < 16) {
            int qrow = q0 + qtl * 16 + n16;
            int gi = b * HWN + qrow;
            atomicAdd(&den_g[gi], dv);
            atomicAdd(&nx_g[gi],  xv);
            atomicAdd(&ny_g[gi],  yv);
        }
    }
}

// ---------------------------------------------------------------------------
__global__ __launch_bounds__(256) void finalize_kernel(
    const float* __restrict__ den_g, const float* __restrict__ nx_g,
    const float* __restrict__ ny_g, float* __restrict__ out)
{
    int idx = blockIdx.x * 256 + threadIdx.x;  // b*HW + n
    int b = idx >> 12, n = idx & 4095;
    float inv = 1.0f / den_g[idx];
    out[(size_t)b * 2 * HWN + n]       = nx_g[idx] * inv;
    out[(size_t)b * 2 * HWN + HWN + n] = ny_g[idx] * inv;
}

extern "C" void kernel_launch(void* const* d_in, const int* in_sizes, int n_in,
                              void* d_out, int out_size, void* d_ws, size_t ws_size,
                              hipStream_t stream) {
    const float* feature = (const float*)d_in[0];
    const float* flow    = (const float*)d_in[1];
    const float* q_w     = (const float*)d_in[2];
    const float* q_b     = (const float*)d_in[3];
    const float* k_w     = (const float*)d_in[4];
    const float* k_b     = (const float*)d_in[5];
    float* out = (float*)d_out;

    ushort_t* qbuf = (ushort_t*)d_ws;                     // [NTOK][CC] bf16, frag-major
    ushort_t* kbuf = qbuf + (size_t)NTOK * CC;            // [NTOK][CC] bf16, frag-major
    float* den = (float*)(kbuf + (size_t)NTOK * CC);      // [NTOK]
    float* nx  = den + NTOK;
    float* ny  = nx + NTOK;
    ushort_t* qwb = (ushort_t*)(ny + NTOK);               // [CC][CC] bf16 (pre-scaled)
    ushort_t* kwb = qwb + (size_t)CC * CC;                // [CC][CC] bf16
    ushort_t* fbuf = kwb + (size_t)CC * CC;               // [NTOK][CC] bf16 token-major

    prep_kernel<<<1088, 256, 0, stream>>>(feature, q_w, k_w, fbuf, qwb, kwb, den);
    proj_kernel<<<1024, 256, 0, stream>>>(fbuf, qwb, kwb, q_b, k_b, qbuf, kbuf);
    attn_kernel<<<1024, 256, 0, stream>>>(qbuf, kbuf, flow, den, nx, ny);
    finalize_kernel<<<64, 256, 0, stream>>>(den, nx, ny, out);
}

// Round 10
// 131.460 us; speedup vs baseline: 1.2910x; 1.2910x over previous
//
#include <hip/hip_runtime.h>
#include <math.h>

#define BB 4
#define CC 256
#define HWN 4096
#define NTOK 16384                 // BB*HWN
#define SCQ 0.09016844136f         // (1/sqrt(256)) * log2(e)

typedef __attribute__((ext_vector_type(8))) short short8;
typedef __attribute__((ext_vector_type(4))) float f32x4;
typedef unsigned short ushort_t;

__device__ __forceinline__ ushort_t f2bf(float f) {
    unsigned int u = __float_as_uint(f);
    unsigned int r = (u + 0x7FFFu + ((u >> 16) & 1u)) >> 16;   // RNE
    return (ushort_t)r;
}
__device__ __forceinline__ unsigned int pack2(float a, float b) {
    return (unsigned int)f2bf(a) | ((unsigned int)f2bf(b) << 16);
}
__device__ __forceinline__ float fexp2(float x) {
#if __has_builtin(__builtin_amdgcn_exp2f)
    return __builtin_amdgcn_exp2f(x);     // single v_exp_f32
#else
    return exp2f(x);
#endif
}

// ---------------------------------------------------------------------------
// wprep (round-1 verified): convert q_w (pre-scaled by SCQ) and k_w to bf16;
// zero den/nx/ny.
// ---------------------------------------------------------------------------
__global__ __launch_bounds__(256) void wprep_kernel(
    const float* __restrict__ q_w, const float* __restrict__ k_w,
    ushort_t* __restrict__ qwb, ushort_t* __restrict__ kwb,
    float* __restrict__ zbuf)
{
    int t = blockIdx.x * 256 + threadIdx.x;          // grid 64 -> 16384 threads
    float4 q4 = *(const float4*)&q_w[(size_t)t * 4];
    float4 k4 = *(const float4*)&k_w[(size_t)t * 4];
    unsigned long long qo = (unsigned long long)pack2(q4.x * SCQ, q4.y * SCQ)
                          | ((unsigned long long)pack2(q4.z * SCQ, q4.w * SCQ) << 32);
    unsigned long long ko = (unsigned long long)pack2(k4.x, k4.y)
                          | ((unsigned long long)pack2(k4.z, k4.w) << 32);
    *(unsigned long long*)&qwb[(size_t)t * 4] = qo;
    *(unsigned long long*)&kwb[(size_t)t * 4] = ko;
    zbuf[t] = 0.f; zbuf[t + NTOK] = 0.f; zbuf[t + 2 * NTOK] = 0.f;
}

// ---------------------------------------------------------------------------
// Fused projection (round-1 verified structure; ONLY the output addressing
// changed to the frag-major granule layout verified in rounds 4-6).
// Block = 64 tokens x 128-d half (twin blocks id, id+256 share (b,tt) and
// the same XCD). Phase 1: stage feature [256c x 64tok] fp32 -> bf16 LDS
// token-major. Phase 2: per wave, 2 x 16-d x 256c MFMA for Q and K with
// pre-converted bf16 weights. Stores: granule g(b,tile16,kc,quad,n16) at
// byte ((b*256+tile)*512 + kc*64 + quadA*16 + n16)*16 + halfo*8.
// ---------------------------------------------------------------------------
__global__ __launch_bounds__(256, 2) void proj_kernel(
    const float* __restrict__ feature,
    const ushort_t* __restrict__ qwb, const ushort_t* __restrict__ kwb,
    const float* __restrict__ q_bias, const float* __restrict__ k_bias,
    ushort_t* __restrict__ qb, ushort_t* __restrict__ kb)
{
    int id = blockIdx.x;
    int dh = id >> 8;            // 0..1: twin blocks 256 apart share (b,tt)
    id &= 255;
    int tt = id & 63;
    int b  = id >> 6;
    int tok0 = tt * 64;

    int t = threadIdx.x, w = t >> 6, lane = t & 63;
    int n16 = lane & 15, quad = lane >> 4;

    __shared__ float    lsA[64][69];    // [c-in-chunk][tok] fp32, stride 69
    __shared__ ushort_t lsB[64][264];   // [tok][c 0..255] bf16, stride 264

    const float* F = feature + (size_t)(b * CC) * HWN;

    int cl = t >> 2, tg = (t & 3) * 16;
    int tokw = t >> 2, c16 = (t & 3) * 16;

    for (int ch = 0; ch < 4; ch++) {
        const float* src = F + (size_t)(ch * 64 + cl) * HWN + tok0 + tg;
        *(float4*)&lsA[cl][tg]      = *(const float4*)(src);
        *(float4*)&lsA[cl][tg + 4]  = *(const float4*)(src + 4);
        *(float4*)&lsA[cl][tg + 8]  = *(const float4*)(src + 8);
        *(float4*)&lsA[cl][tg + 12] = *(const float4*)(src + 12);
        __syncthreads();
        #pragma unroll
        for (int jj = 0; jj < 8; jj++)
            *(unsigned int*)&lsB[tokw][ch * 64 + c16 + 2 * jj] =
                pack2(lsA[c16 + 2 * jj][tokw], lsA[c16 + 2 * jj + 1][tokw]);
        __syncthreads();
    }

    int dw0 = dh * 128 + w * 32;
    #pragma unroll
    for (int dsub = 0; dsub < 2; dsub++) {
        int d0 = dw0 + dsub * 16;
        f32x4 accq[4], acck[4];
        #pragma unroll
        for (int i = 0; i < 4; i++) {
            accq[i] = (f32x4){0.f, 0.f, 0.f, 0.f};
            acck[i] = (f32x4){0.f, 0.f, 0.f, 0.f};
        }
        #pragma unroll
        for (int kc = 0; kc < 8; kc++) {
            size_t off = (size_t)(d0 + n16) * CC + kc * 32 + quad * 8;
            short8 aq = *(const short8*)&qwb[off];
            short8 ak = *(const short8*)&kwb[off];
            #pragma unroll
            for (int tokt = 0; tokt < 4; tokt++) {
                short8 bf = *(const short8*)&lsB[tokt * 16 + n16][kc * 32 + quad * 8];
                accq[tokt] = __builtin_amdgcn_mfma_f32_16x16x32_bf16(aq, bf, accq[tokt], 0, 0, 0);
                acck[tokt] = __builtin_amdgcn_mfma_f32_16x16x32_bf16(ak, bf, acck[tokt], 0, 0, 0);
            }
        }
        float bqv[4], bkv[4];
        #pragma unroll
        for (int r = 0; r < 4; r++) {
            bqv[r] = q_bias[d0 + quad * 4 + r] * SCQ;
            bkv[r] = k_bias[d0 + quad * 4 + r];
        }
        // frag-major store indices (verified formula, rounds 4-6)
        int kcq   = d0 >> 5;
        int quadA = ((d0 >> 4) & 1) * 2 + (quad >> 1);
        int halfo = quad & 1;
        #pragma unroll
        for (int tokt = 0; tokt < 4; tokt++) {
            ushort4 oq, ok;
            oq.x = f2bf(accq[tokt][0] + bqv[0]); oq.y = f2bf(accq[tokt][1] + bqv[1]);
            oq.z = f2bf(accq[tokt][2] + bqv[2]); oq.w = f2bf(accq[tokt][3] + bqv[3]);
            ok.x = f2bf(acck[tokt][0] + bkv[0]); ok.y = f2bf(acck[tokt][1] + bkv[1]);
            ok.z = f2bf(acck[tokt][2] + bkv[2]); ok.w = f2bf(acck[tokt][3] + bkv[3]);
            int tt_tile = tt * 4 + tokt;
            size_t gbyte = (((size_t)(b * 256 + tt_tile) * 512) + kcq * 64 + quadA * 16 + n16) * 16
                           + halfo * 8;
            *(ushort4*)((char*)qb + gbyte) = oq;
            *(ushort4*)((char*)kb + gbyte) = ok;
        }
    }
}

// ---------------------------------------------------------------------------
// Attention (round-6 verified, verbatim): block = (b, 64-q, 1024-key),
// 4 waves = key-quarters; wave = 64q x 256keys. Q staged via global_load_lds
// to LDS once (32 KB, frag-major), read lane-contiguous in the K loop.
// K streamed L2->regs per 32-key round. mfma(K,Q): lane owns 4 keys x 1 q-col.
// No K-loop barriers; partials merged via atomics.
// ---------------------------------------------------------------------------
__global__ __launch_bounds__(256, 2) void attn_kernel(
    const ushort_t* __restrict__ qb, const ushort_t* __restrict__ kb,
    const float* __restrict__ flow,
    float* __restrict__ den_g, float* __restrict__ nx_g, float* __restrict__ ny_g)
{
    int id = (blockIdx.x & 7) * 128 + (blockIdx.x >> 3);   // bijective XCD swizzle
    int qt = id & 63; id >>= 6;       // 64 q-tiles of 64 rows
    int sr = id & 3;  id >>= 2;       // 4 key ranges of 1024
    int b = id;

    int t = threadIdx.x;
    int w = t >> 6, lane = t & 63;
    int n16 = lane & 15, quad = lane >> 4;

    int q0 = qt * 64;
    int s_beg = sr * 1024;

    __shared__ __align__(16) ushort_t qlds[16384];   // 32 KB: 4 q-tiles, frag-major
    __shared__ float lflow[2048];                    // 1024 vx + 1024 vy

    const float* fx = flow + (size_t)b * 2 * HWN;
    const float* fy = fx + HWN;
    #pragma unroll
    for (int i = 0; i < 4; i++) {
        lflow[t + i * 256]        = fx[s_beg + t + i * 256];
        lflow[1024 + t + i * 256] = fy[s_beg + t + i * 256];
    }

    // stage Q block (4 tiles x 512 granules x 16B = 32KB), linear copy
    {
        const char* qsrc = (const char*)qb + ((size_t)(b * 256 + (q0 >> 4)) * 512) * 16;
        char* qdst = (char*)qlds;
        #pragma unroll
        for (int i = 0; i < 8; i++)
            __builtin_amdgcn_global_load_lds(
                (const __attribute__((address_space(1))) unsigned int*)(qsrc + (i * 256 + t) * 16),
                (__attribute__((address_space(3))) unsigned int*)(qdst + (i * 256 + t) * 16),
                16, 0, 0);
    }
    __syncthreads();   // only barrier: Q + flow staged

    // K granule base for this wave's 256-key quarter
    const char* kbase = (const char*)kb
        + ((size_t)(b * 256 + (s_beg >> 4) + w * 16) * 512 + lane) * 16;
    const char* qldsb = (const char*)qlds + (size_t)lane * 16;

    float den[4], nxa[4], nya[4];
    #pragma unroll
    for (int i = 0; i < 4; i++) { den[i] = 0.f; nxa[i] = 0.f; nya[i] = 0.f; }

    for (int round = 0; round < 8; round++) {
        short8 kf0[8], kf1[8];
        #pragma unroll
        for (int kc = 0; kc < 8; kc++) {
            kf0[kc] = *(const short8*)(kbase + (round * 2 + 0) * 8192 + kc * 1024);
            kf1[kc] = *(const short8*)(kbase + (round * 2 + 1) * 8192 + kc * 1024);
        }
        int klbase = w * 256 + round * 32 + quad * 4;
        f32x4 vx0 = *(const f32x4*)&lflow[klbase];
        f32x4 vx1 = *(const f32x4*)&lflow[klbase + 16];
        f32x4 vy0 = *(const f32x4*)&lflow[1024 + klbase];
        f32x4 vy1 = *(const f32x4*)&lflow[1024 + klbase + 16];

        #pragma unroll
        for (int qtl = 0; qtl < 4; qtl++) {
            f32x4 a0 = (f32x4){0.f, 0.f, 0.f, 0.f};
            f32x4 a1 = (f32x4){0.f, 0.f, 0.f, 0.f};
            #pragma unroll
            for (int kc = 0; kc < 8; kc++) {
                short8 qf = *(const short8*)(qldsb + qtl * 8192 + kc * 1024);
                a0 = __builtin_amdgcn_mfma_f32_16x16x32_bf16(kf0[kc], qf, a0, 0, 0, 0);
                a1 = __builtin_amdgcn_mfma_f32_16x16x32_bf16(kf1[kc], qf, a1, 0, 0, 0);
            }
            float d_ = 0.f, x_ = 0.f, y_ = 0.f;
            #pragma unroll
            for (int r = 0; r < 4; r++) {
                float p0 = fexp2(a0[r]);
                float p1 = fexp2(a1[r]);
                d_ += p0 + p1;
                x_ = fmaf(p0, vx0[r], x_); x_ = fmaf(p1, vx1[r], x_);
                y_ = fmaf(p0, vy0[r], y_); y_ = fmaf(p1, vy1[r], y_);
            }
            den[qtl] += d_; nxa[qtl] += x_; nya[qtl] += y_;
        }
    }

    #pragma unroll
    for (int qtl = 0; qtl < 4; qtl++) {
        float dv = den[qtl], xv = nxa[qtl], yv = nya[qtl];
        dv += __shfl_down(dv, 32); dv += __shfl_down(dv, 16);
        xv += __shfl_down(xv, 32); xv += __shfl_down(xv, 16);
        yv += __shfl_down(yv, 32); yv += __shfl_down(yv, 16);
        if (lane < 16) {
            int qrow = q0 + qtl * 16 + n16;
            int gi = b * HWN + qrow;
            atomicAdd(&den_g[gi], dv);
            atomicAdd(&nx_g[gi],  xv);
            atomicAdd(&ny_g[gi],  yv);
        }
    }
}

// ---------------------------------------------------------------------------
__global__ __launch_bounds__(256) void finalize_kernel(
    const float* __restrict__ den_g, const float* __restrict__ nx_g,
    const float* __restrict__ ny_g, float* __restrict__ out)
{
    int idx = blockIdx.x * 256 + threadIdx.x;  // b*HW + n
    int b = idx >> 12, n = idx & 4095;
    float inv = 1.0f / den_g[idx];
    out[(size_t)b * 2 * HWN + n]       = nx_g[idx] * inv;
    out[(size_t)b * 2 * HWN + HWN + n] = ny_g[idx] * inv;
}

extern "C" void kernel_launch(void* const* d_in, const int* in_sizes, int n_in,
                              void* d_out, int out_size, void* d_ws, size_t ws_size,
                              hipStream_t stream) {
    const float* feature = (const float*)d_in[0];
    const float* flow    = (const float*)d_in[1];
    const float* q_w     = (const float*)d_in[2];
    const float* q_b     = (const float*)d_in[3];
    const float* k_w     = (const float*)d_in[4];
    const float* k_b     = (const float*)d_in[5];
    float* out = (float*)d_out;

    ushort_t* qbuf = (ushort_t*)d_ws;                     // [NTOK][CC] bf16, frag-major
    ushort_t* kbuf = qbuf + (size_t)NTOK * CC;            // [NTOK][CC] bf16, frag-major
    float* den = (float*)(kbuf + (size_t)NTOK * CC);      // [NTOK]
    float* nx  = den + NTOK;
    float* ny  = nx + NTOK;
    ushort_t* qwb = (ushort_t*)(ny + NTOK);               // [CC][CC] bf16 (pre-scaled)
    ushort_t* kwb = qwb + (size_t)CC * CC;                // [CC][CC] bf16

    wprep_kernel<<<64, 256, 0, stream>>>(q_w, k_w, qwb, kwb, den);  // + zero den/nx/ny
    proj_kernel<<<512, 256, 0, stream>>>(feature, qwb, kwb, q_b, k_b, qbuf, kbuf);
    attn_kernel<<<1024, 256, 0, stream>>>(qbuf, kbuf, flow, den, nx, ny);
    finalize_kernel<<<64, 256, 0, stream>>>(den, nx, ny, out);
}

// Round 12
// 128.126 us; speedup vs baseline: 1.3246x; 1.0260x over previous
//
#include <hip/hip_runtime.h>
#include <math.h>

#define BB 4
#define CC 256
#define HWN 4096
#define NTOK 16384                 // BB*HWN
#define SCQ 0.09016844136f         // (1/sqrt(256)) * log2(e)

typedef __attribute__((ext_vector_type(8))) short short8;
typedef __attribute__((ext_vector_type(4))) float f32x4;
typedef unsigned short ushort_t;

__device__ __forceinline__ ushort_t f2bf(float f) {
    unsigned int u = __float_as_uint(f);
    unsigned int r = (u + 0x7FFFu + ((u >> 16) & 1u)) >> 16;   // RNE
    return (ushort_t)r;
}
__device__ __forceinline__ unsigned int pack2(float a, float b) {
    return (unsigned int)f2bf(a) | ((unsigned int)f2bf(b) << 16);
}
__device__ __forceinline__ float fexp2(float x) {
#if __has_builtin(__builtin_amdgcn_exp2f)
    return __builtin_amdgcn_exp2f(x);     // single v_exp_f32
#else
    return exp2f(x);
#endif
}

// ---------------------------------------------------------------------------
// wprep (verified): convert q_w (pre-scaled by SCQ) and k_w to bf16;
// zero den/nx/ny.
// ---------------------------------------------------------------------------
__global__ __launch_bounds__(256) void wprep_kernel(
    const float* __restrict__ q_w, const float* __restrict__ k_w,
    ushort_t* __restrict__ qwb, ushort_t* __restrict__ kwb,
    float* __restrict__ zbuf)
{
    int t = blockIdx.x * 256 + threadIdx.x;          // grid 64 -> 16384 threads
    float4 q4 = *(const float4*)&q_w[(size_t)t * 4];
    float4 k4 = *(const float4*)&k_w[(size_t)t * 4];
    unsigned long long qo = (unsigned long long)pack2(q4.x * SCQ, q4.y * SCQ)
                          | ((unsigned long long)pack2(q4.z * SCQ, q4.w * SCQ) << 32);
    unsigned long long ko = (unsigned long long)pack2(k4.x, k4.y)
                          | ((unsigned long long)pack2(k4.z, k4.w) << 32);
    *(unsigned long long*)&qwb[(size_t)t * 4] = qo;
    *(unsigned long long*)&kwb[(size_t)t * 4] = ko;
    zbuf[t] = 0.f; zbuf[t + NTOK] = 0.f; zbuf[t + 2 * NTOK] = 0.f;
}

// ---------------------------------------------------------------------------
// Fused projection v2 (THE ONE CHANGE THIS ROUND): phase 1 converts
// fp32->bf16 DURING staging, writing the transposed lsB directly (lsA
// deleted; 8 barriers -> 1; LDS 51.4 -> 33.8 KB). Phase 2 and the
// frag-major granule stores are byte-identical to round 10 (verified).
// ---------------------------------------------------------------------------
__global__ __launch_bounds__(256, 2) void proj_kernel(
    const float* __restrict__ feature,
    const ushort_t* __restrict__ qwb, const ushort_t* __restrict__ kwb,
    const float* __restrict__ q_bias, const float* __restrict__ k_bias,
    ushort_t* __restrict__ qb, ushort_t* __restrict__ kb)
{
    int id = blockIdx.x;
    int dh = id >> 8;            // 0..1: twin blocks 256 apart share (b,tt)
    id &= 255;
    int tt = id & 63;
    int b  = id >> 6;
    int tok0 = tt * 64;

    int t = threadIdx.x, w = t >> 6, lane = t & 63;
    int n16 = lane & 15, quad = lane >> 4;

    __shared__ ushort_t lsB[64][264];   // [tok][c 0..255] bf16, stride 264

    const float* F = feature + (size_t)(b * CC) * HWN;

    int cl = t >> 2, tg = (t & 3) * 16;

    #pragma unroll
    for (int ch = 0; ch < 4; ch++) {
        const float* src = F + (size_t)(ch * 64 + cl) * HWN + tok0 + tg;
        float4 f0 = *(const float4*)(src);
        float4 f1 = *(const float4*)(src + 4);
        float4 f2 = *(const float4*)(src + 8);
        float4 f3 = *(const float4*)(src + 12);
        int c = ch * 64 + cl;
        lsB[tg + 0][c]  = f2bf(f0.x); lsB[tg + 1][c]  = f2bf(f0.y);
        lsB[tg + 2][c]  = f2bf(f0.z); lsB[tg + 3][c]  = f2bf(f0.w);
        lsB[tg + 4][c]  = f2bf(f1.x); lsB[tg + 5][c]  = f2bf(f1.y);
        lsB[tg + 6][c]  = f2bf(f1.z); lsB[tg + 7][c]  = f2bf(f1.w);
        lsB[tg + 8][c]  = f2bf(f2.x); lsB[tg + 9][c]  = f2bf(f2.y);
        lsB[tg + 10][c] = f2bf(f2.z); lsB[tg + 11][c] = f2bf(f2.w);
        lsB[tg + 12][c] = f2bf(f3.x); lsB[tg + 13][c] = f2bf(f3.y);
        lsB[tg + 14][c] = f2bf(f3.z); lsB[tg + 15][c] = f2bf(f3.w);
    }
    __syncthreads();    // single barrier: lsB complete

    int dw0 = dh * 128 + w * 32;
    #pragma unroll
    for (int dsub = 0; dsub < 2; dsub++) {
        int d0 = dw0 + dsub * 16;
        f32x4 accq[4], acck[4];
        #pragma unroll
        for (int i = 0; i < 4; i++) {
            accq[i] = (f32x4){0.f, 0.f, 0.f, 0.f};
            acck[i] = (f32x4){0.f, 0.f, 0.f, 0.f};
        }
        #pragma unroll
        for (int kc = 0; kc < 8; kc++) {
            size_t off = (size_t)(d0 + n16) * CC + kc * 32 + quad * 8;
            short8 aq = *(const short8*)&qwb[off];
            short8 ak = *(const short8*)&kwb[off];
            #pragma unroll
            for (int tokt = 0; tokt < 4; tokt++) {
                short8 bf = *(const short8*)&lsB[tokt * 16 + n16][kc * 32 + quad * 8];
                accq[tokt] = __builtin_amdgcn_mfma_f32_16x16x32_bf16(aq, bf, accq[tokt], 0, 0, 0);
                acck[tokt] = __builtin_amdgcn_mfma_f32_16x16x32_bf16(ak, bf, acck[tokt], 0, 0, 0);
            }
        }
        float bqv[4], bkv[4];
        #pragma unroll
        for (int r = 0; r < 4; r++) {
            bqv[r] = q_bias[d0 + quad * 4 + r] * SCQ;
            bkv[r] = k_bias[d0 + quad * 4 + r];
        }
        // frag-major store indices (verified formula)
        int kcq   = d0 >> 5;
        int quadA = ((d0 >> 4) & 1) * 2 + (quad >> 1);
        int halfo = quad & 1;
        #pragma unroll
        for (int tokt = 0; tokt < 4; tokt++) {
            ushort4 oq, ok;
            oq.x = f2bf(accq[tokt][0] + bqv[0]); oq.y = f2bf(accq[tokt][1] + bqv[1]);
            oq.z = f2bf(accq[tokt][2] + bqv[2]); oq.w = f2bf(accq[tokt][3] + bqv[3]);
            ok.x = f2bf(acck[tokt][0] + bkv[0]); ok.y = f2bf(acck[tokt][1] + bkv[1]);
            ok.z = f2bf(acck[tokt][2] + bkv[2]); ok.w = f2bf(acck[tokt][3] + bkv[3]);
            int tt_tile = tt * 4 + tokt;
            size_t gbyte = (((size_t)(b * 256 + tt_tile) * 512) + kcq * 64 + quadA * 16 + n16) * 16
                           + halfo * 8;
            *(ushort4*)((char*)qb + gbyte) = oq;
            *(ushort4*)((char*)kb + gbyte) = ok;
        }
    }
}

// ---------------------------------------------------------------------------
// Attention (round-10 verified, VERBATIM — the round-11 prefetch is reverted
// pending bisection): block = (b, 64-q, 1024-key), 4 waves = key-quarters;
// wave = 64q x 256keys. Q staged via global_load_lds to LDS once, read
// lane-contiguous in the K loop. K streamed L2->regs per 32-key round.
// mfma(K,Q): lane owns 4 keys x 1 q-col. No K-loop barriers; atomic merge.
// ---------------------------------------------------------------------------
__global__ __launch_bounds__(256, 2) void attn_kernel(
    const ushort_t* __restrict__ qb, const ushort_t* __restrict__ kb,
    const float* __restrict__ flow,
    float* __restrict__ den_g, float* __restrict__ nx_g, float* __restrict__ ny_g)
{
    int id = (blockIdx.x & 7) * 128 + (blockIdx.x >> 3);   // bijective XCD swizzle
    int qt = id & 63; id >>= 6;       // 64 q-tiles of 64 rows
    int sr = id & 3;  id >>= 2;       // 4 key ranges of 1024
    int b = id;

    int t = threadIdx.x;
    int w = t >> 6, lane = t & 63;
    int n16 = lane & 15, quad = lane >> 4;

    int q0 = qt * 64;
    int s_beg = sr * 1024;

    __shared__ __align__(16) ushort_t qlds[16384];   // 32 KB: 4 q-tiles, frag-major
    __shared__ float lflow[2048];                    // 1024 vx + 1024 vy

    const float* fx = flow + (size_t)b * 2 * HWN;
    const float* fy = fx + HWN;
    #pragma unroll
    for (int i = 0; i < 4; i++) {
        lflow[t + i * 256]        = fx[s_beg + t + i * 256];
        lflow[1024 + t + i * 256] = fy[s_beg + t + i * 256];
    }

    // stage Q block (4 tiles x 512 granules x 16B = 32KB), linear copy
    {
        const char* qsrc = (const char*)qb + ((size_t)(b * 256 + (q0 >> 4)) * 512) * 16;
        char* qdst = (char*)qlds;
        #pragma unroll
        for (int i = 0; i < 8; i++)
            __builtin_amdgcn_global_load_lds(
                (const __attribute__((address_space(1))) unsigned int*)(qsrc + (i * 256 + t) * 16),
                (__attribute__((address_space(3))) unsigned int*)(qdst + (i * 256 + t) * 16),
                16, 0, 0);
    }
    __syncthreads();   // only barrier: Q + flow staged

    // K granule base for this wave's 256-key quarter
    const char* kbase = (const char*)kb
        + ((size_t)(b * 256 + (s_beg >> 4) + w * 16) * 512 + lane) * 16;
    const char* qldsb = (const char*)qlds + (size_t)lane * 16;

    float den[4], nxa[4], nya[4];
    #pragma unroll
    for (int i = 0; i < 4; i++) { den[i] = 0.f; nxa[i] = 0.f; nya[i] = 0.f; }

    for (int round = 0; round < 8; round++) {
        short8 kf0[8], kf1[8];
        #pragma unroll
        for (int kc = 0; kc < 8; kc++) {
            kf0[kc] = *(const short8*)(kbase + (round * 2 + 0) * 8192 + kc * 1024);
            kf1[kc] = *(const short8*)(kbase + (round * 2 + 1) * 8192 + kc * 1024);
        }
        int klbase = w * 256 + round * 32 + quad * 4;
        f32x4 vx0 = *(const f32x4*)&lflow[klbase];
        f32x4 vx1 = *(const f32x4*)&lflow[klbase + 16];
        f32x4 vy0 = *(const f32x4*)&lflow[1024 + klbase];
        f32x4 vy1 = *(const f32x4*)&lflow[1024 + klbase + 16];

        #pragma unroll
        for (int qtl = 0; qtl < 4; qtl++) {
            f32x4 a0 = (f32x4){0.f, 0.f, 0.f, 0.f};
            f32x4 a1 = (f32x4){0.f, 0.f, 0.f, 0.f};
            #pragma unroll
            for (int kc = 0; kc < 8; kc++) {
                short8 qf = *(const short8*)(qldsb + qtl * 8192 + kc * 1024);
                a0 = __builtin_amdgcn_mfma_f32_16x16x32_bf16(kf0[kc], qf, a0, 0, 0, 0);
                a1 = __builtin_amdgcn_mfma_f32_16x16x32_bf16(kf1[kc], qf, a1, 0, 0, 0);
            }
            float d_ = 0.f, x_ = 0.f, y_ = 0.f;
            #pragma unroll
            for (int r = 0; r < 4; r++) {
                float p0 = fexp2(a0[r]);
                float p1 = fexp2(a1[r]);
                d_ += p0 + p1;
                x_ = fmaf(p0, vx0[r], x_); x_ = fmaf(p1, vx1[r], x_);
                y_ = fmaf(p0, vy0[r], y_); y_ = fmaf(p1, vy1[r], y_);
            }
            den[qtl] += d_; nxa[qtl] += x_; nya[qtl] += y_;
        }
    }

    #pragma unroll
    for (int qtl = 0; qtl < 4; qtl++) {
        float dv = den[qtl], xv = nxa[qtl], yv = nya[qtl];
        dv += __shfl_down(dv, 32); dv += __shfl_down(dv, 16);
        xv += __shfl_down(xv, 32); xv += __shfl_down(xv, 16);
        yv += __shfl_down(yv, 32); yv += __shfl_down(yv, 16);
        if (lane < 16) {
            int qrow = q0 + qtl * 16 + n16;
            int gi = b * HWN + qrow;
            atomicAdd(&den_g[gi], dv);
            atomicAdd(&nx_g[gi],  xv);
            atomicAdd(&ny_g[gi],  yv);
        }
    }
}

// ---------------------------------------------------------------------------
__global__ __launch_bounds__(256) void finalize_kernel(
    const float* __restrict__ den_g, const float* __restrict__ nx_g,
    const float* __restrict__ ny_g, float* __restrict__ out)
{
    int idx = blockIdx.x * 256 + threadIdx.x;  // b*HW + n
    int b = idx >> 12, n = idx & 4095;
    float inv = 1.0f / den_g[idx];
    out[(size_t)b * 2 * HWN + n]       = nx_g[idx] * inv;
    out[(size_t)b * 2 * HWN + HWN + n] = ny_g[idx] * inv;
}

extern "C" void kernel_launch(void* const* d_in, const int* in_sizes, int n_in,
                              void* d_out, int out_size, void* d_ws, size_t ws_size,
                              hipStream_t stream) {
    const float* feature = (const float*)d_in[0];
    const float* flow    = (const float*)d_in[1];
    const float* q_w     = (const float*)d_in[2];
    const float* q_b     = (const float*)d_in[3];
    const float* k_w     = (const float*)d_in[4];
    const float* k_b     = (const float*)d_in[5];
    float* out = (float*)d_out;

    ushort_t* qbuf = (ushort_t*)d_ws;                     // [NTOK][CC] bf16, frag-major
    ushort_t* kbuf = qbuf + (size_t)NTOK * CC;            // [NTOK][CC] bf16, frag-major
    float* den = (float*)(kbuf + (size_t)NTOK * CC);      // [NTOK]
    float* nx  = den + NTOK;
    float* ny  = nx + NTOK;
    ushort_t* qwb = (ushort_t*)(ny + NTOK);               // [CC][CC] bf16 (pre-scaled)
    ushort_t* kwb = qwb + (size_t)CC * CC;                // [CC][CC] bf16

    wprep_kernel<<<64, 256, 0, stream>>>(q_w, k_w, qwb, kwb, den);  // + zero den/nx/ny
    proj_kernel<<<512, 256, 0, stream>>>(feature, qwb, kwb, q_b, k_b, qbuf, kbuf);
    attn_kernel<<<1024, 256, 0, stream>>>(qbuf, kbuf, flow, den, nx, ny);
    finalize_kernel<<<64, 256, 0, stream>>>(den, nx, ny, out);
}